// Round 11
// baseline (1844.407 us; speedup 1.0000x reference)
//
#include <hip/hip_runtime.h>

typedef _Float16 half_t;
typedef _Float16 h2 __attribute__((ext_vector_type(2)));
typedef float float4v __attribute__((ext_vector_type(4)));
typedef unsigned uint4v __attribute__((ext_vector_type(4)));

constexpr int NB = 64;    // batch
constexpr int NT = 50;    // steps
constexpr int NS = 256;   // state dim
constexpr int NA = 64;    // action dim
constexpr int NH = 256;   // hypernet hidden
constexpr int NG = 48;    // Chebyshev-Gauss nodes (rho^-48 ~ 2e-9)
constexpr int MA = NS * NS;   // 65536 A-columns
constexpr int MBC = NS * NA;  // 16384 B-columns
constexpr int RSPLIT = 4;     // blocks per rollout chain

constexpr float LO_SCALE = 2048.0f;
constexpr float LO_INV   = 1.0f / 2048.0f;
constexpr float ZC = 1.0f;   // z = ctx + t/50 in [0, 1.98]
constexpr float ZR = 1.05f;  // interval [-0.05, 2.05]
constexpr float PI_F = 3.14159265358979323846f;

#if defined(__has_builtin)
#if __has_builtin(__builtin_amdgcn_fdot2)
#define HAVE_FDOT2 1
#endif
#endif

__device__ __forceinline__ float fdot2f(h2 a, h2 b, float c) {
#ifdef HAVE_FDOT2
  return __builtin_amdgcn_fdot2(a, b, c, false);
#else
  return c + (float)a[0] * (float)b[0] + (float)a[1] * (float)b[1];
#endif
}

__device__ __forceinline__ h2 as_h2(unsigned u) {
  union { unsigned u; h2 v; } X; X.u = u; return X.v;
}
__device__ __forceinline__ void split_hl(float v, unsigned short& hs, unsigned short& ls) {
  half_t hi = (half_t)v;
  half_t lo = (half_t)((v - (float)hi) * LO_SCALE);
  union { half_t h; unsigned short s; } A;
  A.h = hi; hs = A.s;
  A.h = lo; ls = A.s;
}

// coherent-point access (proven in the round-0 kernel)
__device__ __forceinline__ unsigned aload32(const void* p) {
  return __hip_atomic_load((const unsigned*)p, __ATOMIC_RELAXED, __HIP_MEMORY_SCOPE_SYSTEM);
}
__device__ __forceinline__ void astore32(void* p, unsigned v) {
  __hip_atomic_store((unsigned*)p, v, __ATOMIC_RELAXED, __HIP_MEMORY_SCOPE_SYSTEM);
}
#define WAITVM() asm volatile("s_waitcnt vmcnt(0)" ::: "memory")

// ---------------- prep kernels ----------------

__global__ void k_zero(unsigned* __restrict__ p, int n) {
  int idx = blockIdx.x * 256 + threadIdx.x;
  if (idx < n) p[idx] = 0u;
}

__global__ void k_g(const float* __restrict__ W1a, const float* __restrict__ b1a,
                    const float* __restrict__ W1b, const float* __restrict__ b1b,
                    float* __restrict__ Gt, float* __restrict__ Gbt) {
  int g = blockIdx.x, h = threadIdx.x;
  float th = PI_F * (float)(2 * g + 1) / (float)(2 * NG);
  float zg = ZC + ZR * cosf(th);
  Gt[h * NG + g]  = tanhf(zg * W1a[h] + b1a[h]);
  Gbt[h * NG + g] = tanhf(zg * W1b[h] + b1b[h]);
}

__global__ void k_lag(const float* __restrict__ ctx, float* __restrict__ Lf) {
  int idx = blockIdx.x * 256 + threadIdx.x;
  if (idx >= NT * NB) return;
  int t = idx >> 6, b = idx & 63;
  float z = ctx[b] + (float)t / 50.0f;
  float q[NG];
  float den = 0.f;
  int hit = -1;
#pragma unroll
  for (int g = 0; g < NG; ++g) {
    float th = PI_F * (float)(2 * g + 1) / (float)(2 * NG);
    float zg = ZC + ZR * cosf(th);
    float d = z - zg;
    if (fabsf(d) < 1e-7f) hit = g;
    float lam = ((g & 1) ? -1.f : 1.f) * sinf(th);
    float qq = lam / d;
    q[g] = qq;
    den += qq;
  }
  float rden = 1.f / den;
#pragma unroll
  for (int g = 0; g < NG; ++g) {
    float L = (hit >= 0) ? ((g == hit) ? 1.f : 0.f) : q[g] * rden;
    Lf[(size_t)idx * NG + g] = L;
  }
}

// V[t][b][i] = b2b-row(i) . u[t,b]   (bias part of B only)
__global__ void k_v(const float* __restrict__ b2b, const float* __restrict__ us,
                    float* __restrict__ V) {
  int tb = blockIdx.x;
  int t = tb / NB, b = tb % NB;
  int i = threadIdx.x;
  __shared__ float ush[NA];
  if (i < NA) ush[i] = us[((size_t)b * NT + t) * NA + i];
  __syncthreads();
  const float* row = b2b + (size_t)i * NA;
  float s = 0.f;
#pragma unroll 8
  for (int j = 0; j < NA; ++j) s += row[j] * ush[j];
  V[(size_t)tb * NS + i] = s;
}

// u hi/lo in [t][b][j] layout
__global__ void k_u2(const float* __restrict__ usin,
                     unsigned short* __restrict__ uhg, unsigned short* __restrict__ ulg) {
  int idx = blockIdx.x * 256 + threadIdx.x;   // < NT*NB*64
  int j = idx & 63, tb = idx >> 6;
  int t = tb >> 6, b = tb & 63;
  float u = usin[((size_t)b * NT + t) * NA + j];
  unsigned short hs, ls;
  split_hl(u, hs, ls);
  uhg[idx] = hs;
  ulg[idx] = ls;
}

// --- MG two-stage (h-split x4 across blocks) ---
__launch_bounds__(256)
__global__ void k_mg1(const float* __restrict__ W2a, const float* __restrict__ Gt,
                      float* __restrict__ Pp) {
  const int tid = threadIdx.x;
  const int mb = blockIdx.x & 255, hq = blockIdx.x >> 8;
  const size_t m = (size_t)mb * 256 + tid;
  float acc[NG];
#pragma unroll
  for (int g = 0; g < NG; ++g) acc[g] = 0.f;
  const int h0 = hq * 64;
  for (int hh = 0; hh < 64; ++hh) {
    const int h = h0 + hh;
    float w = W2a[(size_t)h * MA + m];
    const float* gr = Gt + h * NG;
#pragma unroll
    for (int g = 0; g < NG; ++g) acc[g] += gr[g] * w;
  }
#pragma unroll
  for (int g = 0; g < NG; ++g)
    Pp[(size_t)(hq * NG + g) * MA + m] = acc[g];
}
__global__ void k_mg2(const float* __restrict__ Pp, float* __restrict__ MGf) {
  const size_t i4 = ((size_t)blockIdx.x * 256 + threadIdx.x) * 4;
  const size_t Q = (size_t)NG * MA;
  float4v s = *(const float4v*)(Pp + i4);
  s += *(const float4v*)(Pp + Q + i4);
  s += *(const float4v*)(Pp + 2 * Q + i4);
  s += *(const float4v*)(Pp + 3 * Q + i4);
  *(float4v*)(MGf + i4) = s;
}
__launch_bounds__(256)
__global__ void k_mgS(const float* __restrict__ W2a, const float* __restrict__ Gt,
                      float* __restrict__ MGf) {
  const int tid = threadIdx.x;
  const size_t m = (size_t)blockIdx.x * 256 + tid;
  float acc[NG];
#pragma unroll
  for (int g = 0; g < NG; ++g) acc[g] = 0.f;
  for (int h = 0; h < NH; ++h) {
    float w = W2a[(size_t)h * MA + m];
    const float* gr = Gt + h * NG;
#pragma unroll
    for (int g = 0; g < NG; ++g) acc[g] += gr[g] * w;
  }
#pragma unroll
  for (int g = 0; g < NG; ++g) MGf[(size_t)g * MA + m] = acc[g];
}

// --- MB two-stage (f32 output) ---
__launch_bounds__(256)
__global__ void k_mb1(const float* __restrict__ W2b, const float* __restrict__ Gbt,
                      float* __restrict__ Pb) {
  const int tid = threadIdx.x;
  const int mb = blockIdx.x & 63, hq = blockIdx.x >> 6;
  const int m = mb * 256 + tid;
  float acc[NG];
#pragma unroll
  for (int g = 0; g < NG; ++g) acc[g] = 0.f;
  const int h0 = hq * 64;
  for (int hh = 0; hh < 64; ++hh) {
    const int h = h0 + hh;
    float w = W2b[(size_t)h * MBC + m];
    const float* gr = Gbt + h * NG;
#pragma unroll
    for (int g = 0; g < NG; ++g) acc[g] += gr[g] * w;
  }
#pragma unroll
  for (int g = 0; g < NG; ++g)
    Pb[(size_t)(hq * NG + g) * MBC + m] = acc[g];
}
__global__ void k_mb2(const float* __restrict__ Pb, float* __restrict__ MBf) {
  const size_t i4 = ((size_t)blockIdx.x * 256 + threadIdx.x) * 4;
  const size_t Q = (size_t)NG * MBC;
  float4v s = *(const float4v*)(Pb + i4);
  s += *(const float4v*)(Pb + Q + i4);
  s += *(const float4v*)(Pb + 2 * Q + i4);
  s += *(const float4v*)(Pb + 3 * Q + i4);
  *(float4v*)(MBf + i4) = s;
}
__launch_bounds__(256)
__global__ void k_mbS(const float* __restrict__ W2b, const float* __restrict__ Gbt,
                      float* __restrict__ MBf) {
  const int tid = threadIdx.x;
  const int m = blockIdx.x * 256 + tid;
  float acc[NG];
#pragma unroll
  for (int g = 0; g < NG; ++g) acc[g] = 0.f;
  for (int h = 0; h < NH; ++h) {
    float w = W2b[(size_t)h * MBC + m];
    const float* gr = Gbt + h * NG;
#pragma unroll
    for (int g = 0; g < NG; ++g) acc[g] += gr[g] * w;
  }
#pragma unroll
  for (int g = 0; g < NG; ++g) MBf[(size_t)g * MBC + m] = acc[g];
}

// x0 -> packed hi|lo into Xp[0]
__global__ void k_x0(const float* __restrict__ x0, unsigned* __restrict__ Xp) {
  int idx = blockIdx.x * 256 + threadIdx.x;
  float x = x0[idx];
  unsigned short hs, ls;
  split_hl(x, hs, ls);
  Xp[idx] = (unsigned)hs | ((unsigned)ls << 16);
}

// ---------------- fused pipeline kernel (512 thr, 2 blocks/CU) ----------------
// blocks [0, 4*NB): rollout — 4 blocks per batch chain, each computes 64 rows;
//   per-step 4-block rendezvous via Xp[t] (system-scope stores) + done[t][b].
// blocks [4*NB, 4*NB+160): pre role — 160 col-units (128 A + 32 B) x 512 cols,
//   full chunk rows, f32 VALU, L staged in LDS 16-row tiles.
// All 416 blocks co-resident (512 thr, <=128 VGPR, ~4.2 KiB LDS -> 2 blocks/CU),
// so polling is deadlock-free by construction.
__launch_bounds__(512, 4)
__global__ void k_pr(const unsigned short* Arh, const unsigned short* Arl,
                     const unsigned short* Brh, const unsigned short* Brl,
                     unsigned short* Awh, unsigned short* Awl,
                     unsigned short* Bwh, unsigned short* Bwl,
                     const float* __restrict__ Lf,
                     const float* __restrict__ MGf, const float* __restrict__ MBf,
                     const float* __restrict__ b2a, const float* __restrict__ V,
                     const unsigned short* __restrict__ uhg,
                     const unsigned short* __restrict__ ulg,
                     unsigned* __restrict__ Xp, unsigned* __restrict__ done,
                     float* __restrict__ out,
                     int nroll, int t0r, int tnr, int t0p, int tnp) {
  __shared__ __align__(16) unsigned short xh[256], xl[256];   // roll x stage
  __shared__ __align__(16) float Lsh[16 * NG];                // pre L tile
  const int tid = threadIdx.x;
  const int bid = blockIdx.x;

  if (bid < nroll) {
    // ===== rollout role: block (b, g) computes rows [g*64, g*64+64) =====
    const int b = bid & 63, g = bid >> 6;
    const int il = tid >> 3, jg = tid & 7;
    const int i = g * 64 + il;
    const int jo = jg * 32;
    for (int tt = 0; tt < tnr; ++tt) {
      const int t = t0r + tt;
      if (tt > 0) {
        if (tid == 0) {
          while (aload32(&done[(size_t)t * NB + b]) < (unsigned)RSPLIT)
            __builtin_amdgcn_s_sleep(2);
        }
      }
      __syncthreads();
      if (tid < 256) {
        unsigned pxx = aload32(&Xp[((size_t)t * NB + b) * NS + tid]);
        xh[tid] = (unsigned short)(pxx & 0xffffu);
        xl[tid] = (unsigned short)(pxx >> 16);
      }
      __syncthreads();
      const int r = tt * NB + b;
      const size_t roA = (size_t)r * MA + (size_t)i * NS + jo;
      const size_t roB = (size_t)r * MBC + (size_t)i * NA + jg * 8;
      const size_t rou = ((size_t)t * NB + b) * NA + jg * 8;
      const float vstep = V[((size_t)t * NB + b) * NS + i];
      uint4v bh = *(const uint4v*)(Brh + roB);
      uint4v bl = *(const uint4v*)(Brl + roB);
      uint4v uh = *(const uint4v*)(uhg + rou);
      uint4v ul = *(const uint4v*)(ulg + rou);
      float s1 = 0.f, s2 = 0.f;
#pragma unroll
      for (int q = 0; q < 4; ++q) {
        uint4v a4 = *(const uint4v*)(Arh + roA + q * 8);
        uint4v c4 = *(const uint4v*)(Arl + roA + q * 8);
        uint4v xh4 = *(const uint4v*)(xh + jo + q * 8);
        uint4v xl4 = *(const uint4v*)(xl + jo + q * 8);
#pragma unroll
        for (int p = 0; p < 4; ++p) {
          s1 = fdot2f(as_h2(a4[p]), as_h2(xh4[p]), s1);
          s2 = fdot2f(as_h2(a4[p]), as_h2(xl4[p]), s2);
          s2 = fdot2f(as_h2(c4[p]), as_h2(xh4[p]), s2);
        }
      }
#pragma unroll
      for (int p = 0; p < 4; ++p) {
        s1 = fdot2f(as_h2(bh[p]), as_h2(uh[p]), s1);
        s2 = fdot2f(as_h2(bh[p]), as_h2(ul[p]), s2);
        s2 = fdot2f(as_h2(bl[p]), as_h2(uh[p]), s2);
      }
      float d = s1 + s2 * LO_INV;
      d += __shfl_xor(d, 1);
      d += __shfl_xor(d, 2);
      d += __shfl_xor(d, 4);
      if (jg == 0) {
        float xn = d + vstep;
        out[((size_t)b * NT + t) * NS + i] = xn;
        unsigned short hs, ls;
        split_hl(xn, hs, ls);
        astore32(&Xp[((size_t)(t + 1) * NB + b) * NS + i],
                 (unsigned)hs | ((unsigned)ls << 16));
      }
      WAITVM();          // own stores at device-visible point
      __syncthreads();   // all waves' stores done
      if (tt + 1 < tnr && tid == 0)
        atomicAdd(&done[(size_t)(t + 1) * NB + b], 1u);
    }
  } else {
    // ===== pre role: f32 VALU materialization of A and B (next chunk) =====
    const int pb = bid - nroll;          // 0..159
    const bool isA = (pb < 128);
    const int m = isA ? (pb * 512 + tid) : ((pb - 128) * 512 + tid);
    const int MC = isA ? MA : MBC;
    const float* __restrict__ MF = isA ? MGf : MBf;
    unsigned short* Wh = isA ? Awh : Bwh;
    unsigned short* Wl = isA ? Awl : Bwl;
    const int R = tnp * NB;              // chunk rows (<=320)
    float4v mg4[NG / 4];
#pragma unroll
    for (int g4 = 0; g4 < NG / 4; ++g4)
#pragma unroll
      for (int k = 0; k < 4; ++k)
        mg4[g4][k] = MF[(size_t)(g4 * 4 + k) * MC + m];
    const float b2v = isA ? b2a[m] : 0.f;
    for (int rt = 0; rt < R; rt += 16) {
      const int nr = (R - rt < 16) ? (R - rt) : 16;
      __syncthreads();
      for (int f = tid; f < nr * NG; f += 512)
        Lsh[f] = Lf[((size_t)(t0p * NB) + rt) * NG + f];
      __syncthreads();
#pragma unroll 4
      for (int rr = 0; rr < nr; ++rr) {
        const float* Lr = Lsh + rr * NG;
        float4v a4 = {0.f, 0.f, 0.f, 0.f};
#pragma unroll
        for (int g4 = 0; g4 < NG / 4; ++g4) {
          float4v L4 = *(const float4v*)(Lr + g4 * 4);
          a4 += L4 * mg4[g4];
        }
        float v = (a4[0] + a4[1]) + (a4[2] + a4[3]) + b2v;
        unsigned short hs, ls;
        split_hl(v, hs, ls);
        const size_t gb = (size_t)(rt + rr) * MC + m;
        Wh[gb] = hs;
        Wl[gb] = ls;
      }
    }
  }
}

// ---------------- launch ----------------

static inline int imin(int a, int b) { return a < b ? a : b; }

extern "C" void kernel_launch(void* const* d_in, const int* in_sizes, int n_in,
                              void* d_out, int out_size, void* d_ws, size_t ws_size,
                              hipStream_t stream) {
  const float* x0  = (const float*)d_in[0];
  const float* ctx = (const float*)d_in[1];
  const float* usin = (const float*)d_in[2];
  const float* W1a = (const float*)d_in[3];
  const float* b1a = (const float*)d_in[4];
  const float* W2a = (const float*)d_in[5];
  const float* b2a = (const float*)d_in[6];
  const float* W1b = (const float*)d_in[7];
  const float* b1b = (const float*)d_in[8];
  const float* W2b = (const float*)d_in[9];
  const float* b2b = (const float*)d_in[10];
  float* out = (float*)d_out;

  const size_t perTA = (size_t)NB * MA * 2;          //  8,388,608 per t (one array)
  const size_t perTB = (size_t)NB * MBC * 2;         //  2,097,152 per t (one array)
  const size_t perTall = 2 * (perTA + perTB);        // 20,971,520
  const size_t szMGf = (size_t)NG * MA * 4;          // 12,582,912
  const size_t szMBf = (size_t)NG * MBC * 4;         //  3,145,728
  const size_t szLf  = (size_t)NT * NB * NG * 4;     //    614,400
  const size_t szGt  = (size_t)NH * NG * 4;          //     49,152 each
  const size_t szU   = (size_t)NT * NB * NA * 2;     //    409,600 each
  const size_t szV   = (size_t)NT * NB * NS * 4;     //  3,276,800
  const size_t szXp  = (size_t)(NT + 1) * NB * NS * 4; // 3,342,336
  const size_t szDn  = (size_t)(NT + 1) * NB * 4;    //     13,056
  const size_t szPp  = (size_t)4 * NG * MA * 4;      // 50,331,648 (aliases A-bufs)
  const size_t szPb  = (size_t)4 * NG * MBC * 4;     // 12,582,912

  const size_t fixed = szMGf + szMBf + szLf + 2 * szGt + 2 * szU + szV + szXp + szDn;

  size_t avail = (ws_size > fixed) ? (ws_size - fixed) : 0;
  bool dbuf = true;
  int Tc = (int)(avail / (2 * perTall));
  if (Tc > 5) Tc = 5;
  if (Tc < 1) {
    dbuf = false;
    Tc = (int)(avail / perTall);
    if (Tc > 5) Tc = 5;
    if (Tc < 1) Tc = 1;
  }

  char* p = (char*)d_ws;
  unsigned short* A0h = (unsigned short*)p; p += (size_t)Tc * perTA;
  unsigned short* A0l = (unsigned short*)p; p += (size_t)Tc * perTA;
  unsigned short* B0h = (unsigned short*)p; p += (size_t)Tc * perTB;
  unsigned short* B0l = (unsigned short*)p; p += (size_t)Tc * perTB;
  unsigned short *A1h = A0h, *A1l = A0l, *B1h = B0h, *B1l = B0l;
  if (dbuf) {
    A1h = (unsigned short*)p; p += (size_t)Tc * perTA;
    A1l = (unsigned short*)p; p += (size_t)Tc * perTA;
    B1h = (unsigned short*)p; p += (size_t)Tc * perTB;
    B1l = (unsigned short*)p; p += (size_t)Tc * perTB;
  }
  float* MGf = (float*)p; p += szMGf;
  float* MBf = (float*)p; p += szMBf;
  float* Lf  = (float*)p; p += szLf;
  float* Gt  = (float*)p; p += szGt;
  float* Gbt = (float*)p; p += szGt;
  unsigned short* uhg = (unsigned short*)p; p += szU;
  unsigned short* ulg = (unsigned short*)p; p += szU;
  float* Vg  = (float*)p; p += szV;
  unsigned* Xp = (unsigned*)p; p += szXp;
  unsigned* done = (unsigned*)p;

  // partial-sum scratch aliases the A/B buffers (used strictly before first k_pr)
  const size_t abbytes = (dbuf ? 2 : 1) * (size_t)Tc * perTall;
  const bool fast_red = abbytes >= (szPp + szPb);
  float* Pp = (float*)A0h;
  float* Pb = Pp + szPp / 4;

  k_zero<<<(int)((szDn / 4 + 255) / 256), 256, 0, stream>>>(done, (int)(szDn / 4));
  k_g<<<NG, NH, 0, stream>>>(W1a, b1a, W1b, b1b, Gt, Gbt);
  k_lag<<<(NT * NB + 255) / 256, 256, 0, stream>>>(ctx, Lf);
  k_v<<<NT * NB, NS, 0, stream>>>(b2b, usin, Vg);
  k_u2<<<(NT * NB * NA) / 256, 256, 0, stream>>>(usin, uhg, ulg);
  k_x0<<<NB, 256, 0, stream>>>(x0, Xp);
  if (fast_red) {
    k_mg1<<<1024, 256, 0, stream>>>(W2a, Gt, Pp);
    k_mg2<<<(int)((size_t)NG * MA / 1024), 256, 0, stream>>>(Pp, MGf);
    k_mb1<<<256, 256, 0, stream>>>(W2b, Gbt, Pb);
    k_mb2<<<(int)((size_t)NG * MBC / 1024), 256, 0, stream>>>(Pb, MBf);
  } else {
    k_mgS<<<MA / 256, 256, 0, stream>>>(W2a, Gt, MGf);
    k_mbS<<<MBC / 256, 256, 0, stream>>>(W2b, Gbt, MBf);
  }

  (void)in_sizes; (void)n_in; (void)out_size;

  const int nc = (NT + Tc - 1) / Tc;
  if (dbuf) {
    // pipelined: launch L runs roll(chunk L-1) || pre(chunk L); 256+160 blocks
    for (int L = 0; L <= nc; ++L) {
      const int rc = L - 1, pc = L;
      const int nroll = (rc >= 0) ? RSPLIT * NB : 0;
      const int t0r = (rc >= 0) ? rc * Tc : 0;
      const int tnr = (rc >= 0) ? imin(Tc, NT - t0r) : 0;
      const int t0p = (pc < nc) ? pc * Tc : 0;
      const int tnp = (pc < nc) ? imin(Tc, NT - t0p) : 0;
      const int grid = nroll + (tnp > 0 ? 160 : 0);
      const unsigned short* Arh = ((rc & 1) ? A1h : A0h);
      const unsigned short* Arl = ((rc & 1) ? A1l : A0l);
      const unsigned short* Brh = ((rc & 1) ? B1h : B0h);
      const unsigned short* Brl = ((rc & 1) ? B1l : B0l);
      unsigned short* Awh = ((pc & 1) ? A1h : A0h);
      unsigned short* Awl = ((pc & 1) ? A1l : A0l);
      unsigned short* Bwh = ((pc & 1) ? B1h : B0h);
      unsigned short* Bwl = ((pc & 1) ? B1l : B0l);
      k_pr<<<grid, 512, 0, stream>>>(Arh, Arl, Brh, Brl, Awh, Awl, Bwh, Bwl,
                                     Lf, MGf, MBf, b2a, Vg, uhg, ulg, Xp, done,
                                     out, nroll, t0r, tnr, t0p, tnp);
    }
  } else {
    for (int c = 0; c < nc; ++c) {
      const int t0 = c * Tc, tn = imin(Tc, NT - t0);
      k_pr<<<160, 512, 0, stream>>>(A0h, A0l, B0h, B0l, A0h, A0l, B0h, B0l,
                                    Lf, MGf, MBf, b2a, Vg, uhg, ulg, Xp, done,
                                    out, 0, 0, 0, t0, tn);
      k_pr<<<RSPLIT * NB, 512, 0, stream>>>(A0h, A0l, B0h, B0l, A0h, A0l, B0h, B0l,
                                            Lf, MGf, MBf, b2a, Vg, uhg, ulg, Xp, done,
                                            out, RSPLIT * NB, t0, tn, 0, 0);
    }
  }
}

// Round 12
// 1139.875 us; speedup vs baseline: 1.6181x; 1.6181x over previous
//
#include <hip/hip_runtime.h>

typedef _Float16 half_t;
typedef _Float16 h2 __attribute__((ext_vector_type(2)));
typedef float float4v __attribute__((ext_vector_type(4)));
typedef unsigned uint4v __attribute__((ext_vector_type(4)));
typedef unsigned uint2v __attribute__((ext_vector_type(2)));

constexpr int NB = 64;    // batch
constexpr int NT = 50;    // steps
constexpr int NS = 256;   // state dim
constexpr int NA = 64;    // action dim
constexpr int NH = 256;   // hypernet hidden
constexpr int NG = 48;    // Chebyshev-Gauss nodes (rho^-48 ~ 2e-9)
constexpr int MA = NS * NS;   // 65536 A-columns
constexpr int MBC = NS * NA;  // 16384 B-columns

constexpr float LO_SCALE = 2048.0f;
constexpr float LO_INV   = 1.0f / 2048.0f;
constexpr float ZC = 1.0f;   // z = ctx + t/50 in [0, 1.98]
constexpr float ZR = 1.05f;  // interval [-0.05, 2.05]
constexpr float PI_F = 3.14159265358979323846f;

#if defined(__has_builtin)
#if __has_builtin(__builtin_amdgcn_fdot2)
#define HAVE_FDOT2 1
#endif
#endif

__device__ __forceinline__ float fdot2f(h2 a, h2 b, float c) {
#ifdef HAVE_FDOT2
  return __builtin_amdgcn_fdot2(a, b, c, false);
#else
  return c + (float)a[0] * (float)b[0] + (float)a[1] * (float)b[1];
#endif
}

__device__ __forceinline__ h2 as_h2(unsigned u) {
  union { unsigned u; h2 v; } X; X.u = u; return X.v;
}
__device__ __forceinline__ void split_hl(float v, unsigned short& hs, unsigned short& ls) {
  half_t hi = (half_t)v;
  half_t lo = (half_t)((v - (float)hi) * LO_SCALE);
  union { half_t h; unsigned short s; } A;
  A.h = hi; hs = A.s;
  A.h = lo; ls = A.s;
}
// f16 bits -> e5m2 byte (RTNE truncation of low mantissa byte)
__device__ __forceinline__ unsigned char lo_e5m2(unsigned short ls) {
  return (unsigned char)((unsigned)(ls + 0x7Fu + ((ls >> 8) & 1u)) >> 8);
}
// decode 4 e5m2 bytes (one u32) -> two h2 pairs {e0,e1}, {e2,e3}
__device__ __forceinline__ void dec4(unsigned v, h2& p01, h2& p23) {
  p01 = as_h2(((v & 0xFFu) << 8) | ((v & 0xFF00u) << 16));
  p23 = as_h2(((v >> 8) & 0xFF00u) | (v & 0xFF000000u));
}

// ---------------- prep kernels ----------------

__global__ void k_g(const float* __restrict__ W1a, const float* __restrict__ b1a,
                    const float* __restrict__ W1b, const float* __restrict__ b1b,
                    float* __restrict__ Gt, float* __restrict__ Gbt) {
  int g = blockIdx.x, h = threadIdx.x;
  float th = PI_F * (float)(2 * g + 1) / (float)(2 * NG);
  float zg = ZC + ZR * cosf(th);
  Gt[h * NG + g]  = tanhf(zg * W1a[h] + b1a[h]);
  Gbt[h * NG + g] = tanhf(zg * W1b[h] + b1b[h]);
}

__global__ void k_lag(const float* __restrict__ ctx, float* __restrict__ Lf) {
  int idx = blockIdx.x * 256 + threadIdx.x;
  if (idx >= NT * NB) return;
  int t = idx >> 6, b = idx & 63;
  float z = ctx[b] + (float)t / 50.0f;
  float q[NG];
  float den = 0.f;
  int hit = -1;
#pragma unroll
  for (int g = 0; g < NG; ++g) {
    float th = PI_F * (float)(2 * g + 1) / (float)(2 * NG);
    float zg = ZC + ZR * cosf(th);
    float d = z - zg;
    if (fabsf(d) < 1e-7f) hit = g;
    float lam = ((g & 1) ? -1.f : 1.f) * sinf(th);
    float qq = lam / d;
    q[g] = qq;
    den += qq;
  }
  float rden = 1.f / den;
#pragma unroll
  for (int g = 0; g < NG; ++g) {
    float L = (hit >= 0) ? ((g == hit) ? 1.f : 0.f) : q[g] * rden;
    Lf[(size_t)idx * NG + g] = L;
  }
}

__global__ void k_v(const float* __restrict__ b2b, const float* __restrict__ us,
                    float* __restrict__ V) {
  int tb = blockIdx.x;
  int t = tb / NB, b = tb % NB;
  int i = threadIdx.x;
  __shared__ float ush[NA];
  if (i < NA) ush[i] = us[((size_t)b * NT + t) * NA + i];
  __syncthreads();
  const float* row = b2b + (size_t)i * NA;
  float s = 0.f;
#pragma unroll 8
  for (int j = 0; j < NA; ++j) s += row[j] * ush[j];
  V[(size_t)tb * NS + i] = s;
}

// u hi/lo f16 in [t][b][j] layout
__global__ void k_u2(const float* __restrict__ usin,
                     unsigned short* __restrict__ uhg, unsigned short* __restrict__ ulg) {
  int idx = blockIdx.x * 256 + threadIdx.x;   // < NT*NB*64
  int j = idx & 63, tb = idx >> 6;
  int t = tb >> 6, b = tb & 63;
  float u = usin[((size_t)b * NT + t) * NA + j];
  unsigned short hs, ls;
  split_hl(u, hs, ls);
  uhg[idx] = hs;
  ulg[idx] = ls;
}

// --- MG two-stage (h-split x4 across blocks) ---
__launch_bounds__(256)
__global__ void k_mg1(const float* __restrict__ W2a, const float* __restrict__ Gt,
                      float* __restrict__ Pp) {
  const int tid = threadIdx.x;
  const int mb = blockIdx.x & 255, hq = blockIdx.x >> 8;
  const size_t m = (size_t)mb * 256 + tid;
  float acc[NG];
#pragma unroll
  for (int g = 0; g < NG; ++g) acc[g] = 0.f;
  const int h0 = hq * 64;
  for (int hh = 0; hh < 64; ++hh) {
    const int h = h0 + hh;
    float w = W2a[(size_t)h * MA + m];
    const float* gr = Gt + h * NG;
#pragma unroll
    for (int g = 0; g < NG; ++g) acc[g] += gr[g] * w;
  }
#pragma unroll
  for (int g = 0; g < NG; ++g)
    Pp[(size_t)(hq * NG + g) * MA + m] = acc[g];
}
__global__ void k_mg2(const float* __restrict__ Pp, float* __restrict__ MGf) {
  const size_t i4 = ((size_t)blockIdx.x * 256 + threadIdx.x) * 4;
  const size_t Q = (size_t)NG * MA;
  float4v s = *(const float4v*)(Pp + i4);
  s += *(const float4v*)(Pp + Q + i4);
  s += *(const float4v*)(Pp + 2 * Q + i4);
  s += *(const float4v*)(Pp + 3 * Q + i4);
  *(float4v*)(MGf + i4) = s;
}
__launch_bounds__(256)
__global__ void k_mgS(const float* __restrict__ W2a, const float* __restrict__ Gt,
                      float* __restrict__ MGf) {
  const int tid = threadIdx.x;
  const size_t m = (size_t)blockIdx.x * 256 + tid;
  float acc[NG];
#pragma unroll
  for (int g = 0; g < NG; ++g) acc[g] = 0.f;
  for (int h = 0; h < NH; ++h) {
    float w = W2a[(size_t)h * MA + m];
    const float* gr = Gt + h * NG;
#pragma unroll
    for (int g = 0; g < NG; ++g) acc[g] += gr[g] * w;
  }
#pragma unroll
  for (int g = 0; g < NG; ++g) MGf[(size_t)g * MA + m] = acc[g];
}

// --- MB two-stage (f32 output) ---
__launch_bounds__(256)
__global__ void k_mb1(const float* __restrict__ W2b, const float* __restrict__ Gbt,
                      float* __restrict__ Pb) {
  const int tid = threadIdx.x;
  const int mb = blockIdx.x & 63, hq = blockIdx.x >> 6;
  const int m = mb * 256 + tid;
  float acc[NG];
#pragma unroll
  for (int g = 0; g < NG; ++g) acc[g] = 0.f;
  const int h0 = hq * 64;
  for (int hh = 0; hh < 64; ++hh) {
    const int h = h0 + hh;
    float w = W2b[(size_t)h * MBC + m];
    const float* gr = Gbt + h * NG;
#pragma unroll
    for (int g = 0; g < NG; ++g) acc[g] += gr[g] * w;
  }
#pragma unroll
  for (int g = 0; g < NG; ++g)
    Pb[(size_t)(hq * NG + g) * MBC + m] = acc[g];
}
__global__ void k_mb2(const float* __restrict__ Pb, float* __restrict__ MBf) {
  const size_t i4 = ((size_t)blockIdx.x * 256 + threadIdx.x) * 4;
  const size_t Q = (size_t)NG * MBC;
  float4v s = *(const float4v*)(Pb + i4);
  s += *(const float4v*)(Pb + Q + i4);
  s += *(const float4v*)(Pb + 2 * Q + i4);
  s += *(const float4v*)(Pb + 3 * Q + i4);
  *(float4v*)(MBf + i4) = s;
}
__launch_bounds__(256)
__global__ void k_mbS(const float* __restrict__ W2b, const float* __restrict__ Gbt,
                      float* __restrict__ MBf) {
  const int tid = threadIdx.x;
  const int m = blockIdx.x * 256 + tid;
  float acc[NG];
#pragma unroll
  for (int g = 0; g < NG; ++g) acc[g] = 0.f;
  for (int h = 0; h < NH; ++h) {
    float w = W2b[(size_t)h * MBC + m];
    const float* gr = Gbt + h * NG;
#pragma unroll
    for (int g = 0; g < NG; ++g) acc[g] += gr[g] * w;
  }
#pragma unroll
  for (int g = 0; g < NG; ++g) MBf[(size_t)g * MBC + m] = acc[g];
}

// x0 -> packed hi|lo state
__global__ void k_x0(const float* __restrict__ x0, unsigned* __restrict__ Xst) {
  int idx = blockIdx.x * 256 + threadIdx.x;
  float x = x0[idx];
  unsigned short hs, ls;
  split_hl(x, hs, ls);
  Xst[idx] = (unsigned)hs | ((unsigned)ls << 16);
}

// ---------------- fused pipeline kernel (1024 thr) ----------------
// blocks [0, nroll): rollout chains (16 waves; thread = (i = tid>>2, jq = tid&3)).
//   A/B hi = f16, lo = e5m2 bytes (decode = byte<<8).
// blocks [nroll, nroll+160): pre role — 80 col-units (64 A + 16 B) x 2 halves;
//   thread-per-column f32 VALU; L staged in LDS 16-row tiles.
__launch_bounds__(1024)
__global__ void k_pr(const unsigned short* Arh, const unsigned char* Arl,
                     const unsigned short* Brh, const unsigned char* Brl,
                     unsigned short* Awh, unsigned char* Awl,
                     unsigned short* Bwh, unsigned char* Bwl,
                     const float* __restrict__ Lf,
                     const float* __restrict__ MGf, const float* __restrict__ MBf,
                     const float* __restrict__ b2a, const float* __restrict__ V,
                     const unsigned short* __restrict__ uhg,
                     const unsigned short* __restrict__ ulg,
                     unsigned* __restrict__ Xst, float* __restrict__ out,
                     int nroll, int t0r, int tnr, int t0p, int tnp) {
  __shared__ __align__(16) unsigned short xb[1024];   // roll x (hi/lo, dbuf)
  __shared__ __align__(16) float Lsh[16 * NG];        // pre L tile
  const int tid = threadIdx.x;
  const int bid = blockIdx.x;

  if (bid < nroll) {
    // ===== rollout role =====
    __builtin_amdgcn_s_setprio(1);
    const int b = bid;
    const int i = tid >> 2, jq = tid & 3;
    if (tid < 256) {
      unsigned pxx = Xst[b * 256 + tid];
      xb[tid] = (unsigned short)(pxx & 0xffffu);
      xb[512 + tid] = (unsigned short)(pxx >> 16);
    }
    __syncthreads();
    int cur = 0;
    for (int tt = 0; tt < tnr; ++tt) {
      const int t = t0r + tt;
      const int r = tt * NB + b;
      const size_t roA = (size_t)r * MA + (size_t)i * NS + jq * 64;
      const size_t roB = (size_t)r * MBC + (size_t)i * NA + jq * 16;
      const size_t rou = ((size_t)t * NB + b) * NA + jq * 16;
      const float vstep = V[((size_t)t * NB + b) * NS + i];
      uint4v bh0 = *(const uint4v*)(Brh + roB);
      uint4v bh1 = *(const uint4v*)(Brh + roB + 8);
      uint4v blB = *(const uint4v*)(Brl + roB);        // 16 e5m2 bytes
      uint4v uh0 = *(const uint4v*)(uhg + rou);
      uint4v uh1 = *(const uint4v*)(uhg + rou + 8);
      uint4v ul0 = *(const uint4v*)(ulg + rou);
      uint4v ul1 = *(const uint4v*)(ulg + rou + 8);
      const unsigned short* xhp = xb + cur * 256 + jq * 64;
      const unsigned short* xlp = xb + 512 + cur * 256 + jq * 64;
      float s1 = 0.f, s2 = 0.f;
#pragma unroll
      for (int q = 0; q < 8; ++q) {
        uint4v a4 = *(const uint4v*)(Arh + roA + q * 8);
        uint2v l2 = *(const uint2v*)(Arl + roA + q * 8);  // 8 e5m2 bytes
        uint4v xh4 = *(const uint4v*)(xhp + q * 8);
        uint4v xl4 = *(const uint4v*)(xlp + q * 8);
#pragma unroll
        for (int p = 0; p < 4; ++p) {
          s1 = fdot2f(as_h2(a4[p]), as_h2(xh4[p]), s1);
          s2 = fdot2f(as_h2(a4[p]), as_h2(xl4[p]), s2);
        }
        h2 p01, p23;
        dec4(l2[0], p01, p23);
        s2 = fdot2f(p01, as_h2(xh4[0]), s2);
        s2 = fdot2f(p23, as_h2(xh4[1]), s2);
        dec4(l2[1], p01, p23);
        s2 = fdot2f(p01, as_h2(xh4[2]), s2);
        s2 = fdot2f(p23, as_h2(xh4[3]), s2);
      }
      // B·u (16 cols per thread)
#pragma unroll
      for (int p = 0; p < 4; ++p) {
        s1 = fdot2f(as_h2(bh0[p]), as_h2(uh0[p]), s1);
        s2 = fdot2f(as_h2(bh0[p]), as_h2(ul0[p]), s2);
        s1 = fdot2f(as_h2(bh1[p]), as_h2(uh1[p]), s1);
        s2 = fdot2f(as_h2(bh1[p]), as_h2(ul1[p]), s2);
      }
      {
        h2 p01, p23;
        dec4(blB[0], p01, p23);
        s2 = fdot2f(p01, as_h2(uh0[0]), s2);
        s2 = fdot2f(p23, as_h2(uh0[1]), s2);
        dec4(blB[1], p01, p23);
        s2 = fdot2f(p01, as_h2(uh0[2]), s2);
        s2 = fdot2f(p23, as_h2(uh0[3]), s2);
        dec4(blB[2], p01, p23);
        s2 = fdot2f(p01, as_h2(uh1[0]), s2);
        s2 = fdot2f(p23, as_h2(uh1[1]), s2);
        dec4(blB[3], p01, p23);
        s2 = fdot2f(p01, as_h2(uh1[2]), s2);
        s2 = fdot2f(p23, as_h2(uh1[3]), s2);
      }
      float d = s1 + s2 * LO_INV;
      d += __shfl_xor(d, 1);
      d += __shfl_xor(d, 2);
      if (jq == 0) {
        float xn = d + vstep;
        out[((size_t)b * NT + t) * NS + i] = xn;
        unsigned short hs, ls;
        split_hl(xn, hs, ls);
        xb[(cur ^ 1) * 256 + i] = hs;
        xb[512 + (cur ^ 1) * 256 + i] = ls;
      }
      __syncthreads();
      cur ^= 1;
    }
    if (tid < 256) {
      unsigned pxx = (unsigned)xb[cur * 256 + tid] |
                     ((unsigned)xb[512 + cur * 256 + tid] << 16);
      Xst[b * 256 + tid] = pxx;
    }
    __builtin_amdgcn_s_setprio(0);
  } else {
    // ===== pre role: f32 VALU materialization of A and B (next chunk) =====
    const int pb = bid - nroll;          // 0..159
    const int cu = pb >> 1, hf = pb & 1;
    const int R = tnp * NB;              // chunk rows
    const int per = (R + 1) >> 1;
    const int r0 = hf * per;
    const int r1 = (r0 + per < R) ? (r0 + per) : R;
    const bool isA = (cu < 64);
    const int m = isA ? (cu * 1024 + tid) : ((cu - 64) * 1024 + tid);
    const int MC = isA ? MA : MBC;
    const float* __restrict__ MF = isA ? MGf : MBf;
    unsigned short* Wh = isA ? Awh : Bwh;
    unsigned char* Wl = isA ? Awl : Bwl;
    float4v mg4[NG / 4];
#pragma unroll
    for (int g4 = 0; g4 < NG / 4; ++g4)
#pragma unroll
      for (int k = 0; k < 4; ++k)
        mg4[g4][k] = MF[(size_t)(g4 * 4 + k) * MC + m];
    const float b2v = isA ? b2a[m] : 0.f;
    for (int rt = r0; rt < r1; rt += 16) {
      const int nr = (r1 - rt < 16) ? (r1 - rt) : 16;
      __syncthreads();
      if (tid < nr * NG)
        Lsh[tid] = Lf[((size_t)(t0p * NB) + rt) * NG + tid];
      __syncthreads();
#pragma unroll 4
      for (int rr = 0; rr < nr; ++rr) {
        const float* Lr = Lsh + rr * NG;
        float4v a4 = {0.f, 0.f, 0.f, 0.f};
#pragma unroll
        for (int g4 = 0; g4 < NG / 4; ++g4) {
          float4v L4 = *(const float4v*)(Lr + g4 * 4);
          a4 += L4 * mg4[g4];
        }
        float v = (a4[0] + a4[1]) + (a4[2] + a4[3]) + b2v;
        unsigned short hs, ls;
        split_hl(v, hs, ls);
        const size_t gb = (size_t)(rt + rr) * MC + m;
        Wh[gb] = hs;
        Wl[gb] = lo_e5m2(ls);
      }
    }
  }
}

// ---------------- launch ----------------

static inline int imin(int a, int b) { return a < b ? a : b; }

extern "C" void kernel_launch(void* const* d_in, const int* in_sizes, int n_in,
                              void* d_out, int out_size, void* d_ws, size_t ws_size,
                              hipStream_t stream) {
  const float* x0  = (const float*)d_in[0];
  const float* ctx = (const float*)d_in[1];
  const float* usin = (const float*)d_in[2];
  const float* W1a = (const float*)d_in[3];
  const float* b1a = (const float*)d_in[4];
  const float* W2a = (const float*)d_in[5];
  const float* b2a = (const float*)d_in[6];
  const float* W1b = (const float*)d_in[7];
  const float* b1b = (const float*)d_in[8];
  const float* W2b = (const float*)d_in[9];
  const float* b2b = (const float*)d_in[10];
  float* out = (float*)d_out;

  const size_t perTAh = (size_t)NB * MA * 2;         //  8,388,608 per t
  const size_t perTAl = (size_t)NB * MA;             //  4,194,304 per t
  const size_t perTBh = (size_t)NB * MBC * 2;        //  2,097,152 per t
  const size_t perTBl = (size_t)NB * MBC;            //  1,048,576 per t
  const size_t perTall = perTAh + perTAl + perTBh + perTBl;  // 15,728,640
  const size_t szMGf = (size_t)NG * MA * 4;          // 12,582,912
  const size_t szMBf = (size_t)NG * MBC * 4;         //  3,145,728
  const size_t szLf  = (size_t)NT * NB * NG * 4;     //    614,400
  const size_t szGt  = (size_t)NH * NG * 4;          //     49,152 each
  const size_t szU   = (size_t)NT * NB * NA * 2;     //    409,600 each
  const size_t szV   = (size_t)NT * NB * NS * 4;     //  3,276,800
  const size_t szXst = (size_t)NB * NS * 4;          //     65,536
  const size_t szPp  = (size_t)4 * NG * MA * 4;      // 50,331,648 (aliases A-bufs)
  const size_t szPb  = (size_t)4 * NG * MBC * 4;     // 12,582,912

  const size_t fixed = szMGf + szMBf + szLf + 2 * szGt + 2 * szU + szV + szXst;

  size_t avail = (ws_size > fixed) ? (ws_size - fixed) : 0;
  bool dbuf = true;
  int Tc = (int)(avail / (2 * perTall));
  if (Tc > 5) Tc = 5;   // 2 x 78.6 MB live A/B set — comfortably L3-resident
  if (Tc < 1) {
    dbuf = false;
    Tc = (int)(avail / perTall);
    if (Tc > 5) Tc = 5;
    if (Tc < 1) Tc = 1;
  }

  char* p = (char*)d_ws;
  unsigned short* A0h = (unsigned short*)p; p += (size_t)Tc * perTAh;
  unsigned char*  A0l = (unsigned char*)p;  p += (size_t)Tc * perTAl;
  unsigned short* B0h = (unsigned short*)p; p += (size_t)Tc * perTBh;
  unsigned char*  B0l = (unsigned char*)p;  p += (size_t)Tc * perTBl;
  unsigned short *A1h = A0h, *B1h = B0h;
  unsigned char  *A1l = A0l, *B1l = B0l;
  if (dbuf) {
    A1h = (unsigned short*)p; p += (size_t)Tc * perTAh;
    A1l = (unsigned char*)p;  p += (size_t)Tc * perTAl;
    B1h = (unsigned short*)p; p += (size_t)Tc * perTBh;
    B1l = (unsigned char*)p;  p += (size_t)Tc * perTBl;
  }
  float* MGf = (float*)p; p += szMGf;
  float* MBf = (float*)p; p += szMBf;
  float* Lf  = (float*)p; p += szLf;
  float* Gt  = (float*)p; p += szGt;
  float* Gbt = (float*)p; p += szGt;
  unsigned short* uhg = (unsigned short*)p; p += szU;
  unsigned short* ulg = (unsigned short*)p; p += szU;
  float* Vg  = (float*)p; p += szV;
  unsigned* Xst = (unsigned*)p;

  // partial-sum scratch aliases the A/B buffers (used strictly before first k_pr)
  const size_t abbytes = (dbuf ? 2 : 1) * (size_t)Tc * perTall;
  const bool fast_red = abbytes >= (szPp + szPb);
  float* Pp = (float*)A0h;
  float* Pb = Pp + szPp / 4;

  k_g<<<NG, NH, 0, stream>>>(W1a, b1a, W1b, b1b, Gt, Gbt);
  k_lag<<<(NT * NB + 255) / 256, 256, 0, stream>>>(ctx, Lf);
  k_v<<<NT * NB, NS, 0, stream>>>(b2b, usin, Vg);
  k_u2<<<(NT * NB * NA) / 256, 256, 0, stream>>>(usin, uhg, ulg);
  k_x0<<<NB, 256, 0, stream>>>(x0, Xst);
  if (fast_red) {
    k_mg1<<<1024, 256, 0, stream>>>(W2a, Gt, Pp);
    k_mg2<<<(int)((size_t)NG * MA / 1024), 256, 0, stream>>>(Pp, MGf);
    k_mb1<<<256, 256, 0, stream>>>(W2b, Gbt, Pb);
    k_mb2<<<(int)((size_t)NG * MBC / 1024), 256, 0, stream>>>(Pb, MBf);
  } else {
    k_mgS<<<MA / 256, 256, 0, stream>>>(W2a, Gt, MGf);
    k_mbS<<<MBC / 256, 256, 0, stream>>>(W2b, Gbt, MBf);
  }

  (void)in_sizes; (void)n_in; (void)out_size;

  const int nc = (NT + Tc - 1) / Tc;
  if (dbuf) {
    // pipelined: launch L runs roll(chunk L-1) || pre(chunk L); 64+160 blocks
    for (int L = 0; L <= nc; ++L) {
      const int rc = L - 1, pc = L;
      const int nroll = (rc >= 0) ? NB : 0;
      const int t0r = (rc >= 0) ? rc * Tc : 0;
      const int tnr = (rc >= 0) ? imin(Tc, NT - t0r) : 0;
      const int t0p = (pc < nc) ? pc * Tc : 0;
      const int tnp = (pc < nc) ? imin(Tc, NT - t0p) : 0;
      const int grid = nroll + (tnp > 0 ? 160 : 0);
      const unsigned short* Arh = ((rc & 1) ? A1h : A0h);
      const unsigned char*  Arl = ((rc & 1) ? A1l : A0l);
      const unsigned short* Brh = ((rc & 1) ? B1h : B0h);
      const unsigned char*  Brl = ((rc & 1) ? B1l : B0l);
      unsigned short* Awh = ((pc & 1) ? A1h : A0h);
      unsigned char*  Awl = ((pc & 1) ? A1l : A0l);
      unsigned short* Bwh = ((pc & 1) ? B1h : B0h);
      unsigned char*  Bwl = ((pc & 1) ? B1l : B0l);
      k_pr<<<grid, 1024, 0, stream>>>(Arh, Arl, Brh, Brl, Awh, Awl, Bwh, Bwl,
                                      Lf, MGf, MBf, b2a, Vg, uhg, ulg, Xst, out,
                                      nroll, t0r, tnr, t0p, tnp);
    }
  } else {
    for (int c = 0; c < nc; ++c) {
      const int t0 = c * Tc, tn = imin(Tc, NT - t0);
      k_pr<<<160, 1024, 0, stream>>>(A0h, A0l, B0h, B0l, A0h, A0l, B0h, B0l,
                                     Lf, MGf, MBf, b2a, Vg, uhg, ulg, Xst, out,
                                     0, 0, 0, t0, tn);
      k_pr<<<NB, 1024, 0, stream>>>(A0h, A0l, B0h, B0l, A0h, A0l, B0h, B0l,
                                    Lf, MGf, MBf, b2a, Vg, uhg, ulg, Xst, out,
                                    NB, t0, tn, 0, 0);
    }
  }
}

// Round 13
// 770.109 us; speedup vs baseline: 2.3950x; 1.4801x over previous
//
#include <hip/hip_runtime.h>

typedef _Float16 half_t;
typedef _Float16 h2 __attribute__((ext_vector_type(2)));
typedef float float4v __attribute__((ext_vector_type(4)));
typedef unsigned uint4v __attribute__((ext_vector_type(4)));
typedef unsigned uint2v __attribute__((ext_vector_type(2)));

constexpr int NB = 64;    // batch
constexpr int NT = 50;    // steps
constexpr int NS = 256;   // state dim
constexpr int NA = 64;    // action dim
constexpr int NH = 256;   // hypernet hidden
constexpr int NG = 32;    // Chebyshev-Gauss nodes (rho^-32 ~ 7e-6 rel, << f16-lo floor)
constexpr int MA = NS * NS;   // 65536 A-columns
constexpr int MBC = NS * NA;  // 16384 B-columns

constexpr float LO_SCALE = 2048.0f;
constexpr float LO_INV   = 1.0f / 2048.0f;
constexpr float ZC = 1.0f;   // z = ctx + t/50 in [0, 1.98]
constexpr float ZR = 1.05f;  // interval [-0.05, 2.05]
constexpr float PI_F = 3.14159265358979323846f;

#if defined(__has_builtin)
#if __has_builtin(__builtin_amdgcn_fdot2)
#define HAVE_FDOT2 1
#endif
#endif

__device__ __forceinline__ float fdot2f(h2 a, h2 b, float c) {
#ifdef HAVE_FDOT2
  return __builtin_amdgcn_fdot2(a, b, c, false);
#else
  return c + (float)a[0] * (float)b[0] + (float)a[1] * (float)b[1];
#endif
}

__device__ __forceinline__ h2 as_h2(unsigned u) {
  union { unsigned u; h2 v; } X; X.u = u; return X.v;
}
__device__ __forceinline__ void split_hl(float v, unsigned short& hs, unsigned short& ls) {
  half_t hi = (half_t)v;
  half_t lo = (half_t)((v - (float)hi) * LO_SCALE);
  union { half_t h; unsigned short s; } A;
  A.h = hi; hs = A.s;
  A.h = lo; ls = A.s;
}
// f16 bits -> e5m2 byte (RTNE truncation of low mantissa byte)
__device__ __forceinline__ unsigned char lo_e5m2(unsigned short ls) {
  return (unsigned char)((unsigned)(ls + 0x7Fu + ((ls >> 8) & 1u)) >> 8);
}
// decode 4 e5m2 bytes (one u32) -> two h2 pairs {e0,e1}, {e2,e3}
__device__ __forceinline__ void dec4(unsigned v, h2& p01, h2& p23) {
  p01 = as_h2(((v & 0xFFu) << 8) | ((v & 0xFF00u) << 16));
  p23 = as_h2(((v >> 8) & 0xFF00u) | (v & 0xFF000000u));
}

// ---------------- prep kernels ----------------

__global__ void k_g(const float* __restrict__ W1a, const float* __restrict__ b1a,
                    const float* __restrict__ W1b, const float* __restrict__ b1b,
                    float* __restrict__ Gt, float* __restrict__ Gbt) {
  int g = blockIdx.x, h = threadIdx.x;
  float th = PI_F * (float)(2 * g + 1) / (float)(2 * NG);
  float zg = ZC + ZR * cosf(th);
  Gt[h * NG + g]  = tanhf(zg * W1a[h] + b1a[h]);
  Gbt[h * NG + g] = tanhf(zg * W1b[h] + b1b[h]);
}

__global__ void k_lag(const float* __restrict__ ctx, float* __restrict__ Lf) {
  int idx = blockIdx.x * 256 + threadIdx.x;
  if (idx >= NT * NB) return;
  int t = idx >> 6, b = idx & 63;
  float z = ctx[b] + (float)t / 50.0f;
  float q[NG];
  float den = 0.f;
  int hit = -1;
#pragma unroll
  for (int g = 0; g < NG; ++g) {
    float th = PI_F * (float)(2 * g + 1) / (float)(2 * NG);
    float zg = ZC + ZR * cosf(th);
    float d = z - zg;
    if (fabsf(d) < 1e-7f) hit = g;
    float lam = ((g & 1) ? -1.f : 1.f) * sinf(th);
    float qq = lam / d;
    q[g] = qq;
    den += qq;
  }
  float rden = 1.f / den;
#pragma unroll
  for (int g = 0; g < NG; ++g) {
    float L = (hit >= 0) ? ((g == hit) ? 1.f : 0.f) : q[g] * rden;
    Lf[(size_t)idx * NG + g] = L;
  }
}

__global__ void k_v(const float* __restrict__ b2b, const float* __restrict__ us,
                    float* __restrict__ V) {
  int tb = blockIdx.x;
  int t = tb / NB, b = tb % NB;
  int i = threadIdx.x;
  __shared__ float ush[NA];
  if (i < NA) ush[i] = us[((size_t)b * NT + t) * NA + i];
  __syncthreads();
  const float* row = b2b + (size_t)i * NA;
  float s = 0.f;
#pragma unroll 8
  for (int j = 0; j < NA; ++j) s += row[j] * ush[j];
  V[(size_t)tb * NS + i] = s;
}

// u hi/lo f16 in [t][b][j] layout
__global__ void k_u2(const float* __restrict__ usin,
                     unsigned short* __restrict__ uhg, unsigned short* __restrict__ ulg) {
  int idx = blockIdx.x * 256 + threadIdx.x;   // < NT*NB*64
  int j = idx & 63, tb = idx >> 6;
  int t = tb >> 6, b = tb & 63;
  float u = usin[((size_t)b * NT + t) * NA + j];
  unsigned short hs, ls;
  split_hl(u, hs, ls);
  uhg[idx] = hs;
  ulg[idx] = ls;
}

// --- MG two-stage (h-split x4 across blocks) ---
__launch_bounds__(256)
__global__ void k_mg1(const float* __restrict__ W2a, const float* __restrict__ Gt,
                      float* __restrict__ Pp) {
  const int tid = threadIdx.x;
  const int mb = blockIdx.x & 255, hq = blockIdx.x >> 8;
  const size_t m = (size_t)mb * 256 + tid;
  float acc[NG];
#pragma unroll
  for (int g = 0; g < NG; ++g) acc[g] = 0.f;
  const int h0 = hq * 64;
  for (int hh = 0; hh < 64; ++hh) {
    const int h = h0 + hh;
    float w = W2a[(size_t)h * MA + m];
    const float* gr = Gt + h * NG;
#pragma unroll
    for (int g = 0; g < NG; ++g) acc[g] += gr[g] * w;
  }
#pragma unroll
  for (int g = 0; g < NG; ++g)
    Pp[(size_t)(hq * NG + g) * MA + m] = acc[g];
}
__global__ void k_mg2(const float* __restrict__ Pp, float* __restrict__ MGf) {
  const size_t i4 = ((size_t)blockIdx.x * 256 + threadIdx.x) * 4;
  const size_t Q = (size_t)NG * MA;
  float4v s = *(const float4v*)(Pp + i4);
  s += *(const float4v*)(Pp + Q + i4);
  s += *(const float4v*)(Pp + 2 * Q + i4);
  s += *(const float4v*)(Pp + 3 * Q + i4);
  *(float4v*)(MGf + i4) = s;
}
__launch_bounds__(256)
__global__ void k_mgS(const float* __restrict__ W2a, const float* __restrict__ Gt,
                      float* __restrict__ MGf) {
  const int tid = threadIdx.x;
  const size_t m = (size_t)blockIdx.x * 256 + tid;
  float acc[NG];
#pragma unroll
  for (int g = 0; g < NG; ++g) acc[g] = 0.f;
  for (int h = 0; h < NH; ++h) {
    float w = W2a[(size_t)h * MA + m];
    const float* gr = Gt + h * NG;
#pragma unroll
    for (int g = 0; g < NG; ++g) acc[g] += gr[g] * w;
  }
#pragma unroll
  for (int g = 0; g < NG; ++g) MGf[(size_t)g * MA + m] = acc[g];
}

// --- MB two-stage (f32 output) ---
__launch_bounds__(256)
__global__ void k_mb1(const float* __restrict__ W2b, const float* __restrict__ Gbt,
                      float* __restrict__ Pb) {
  const int tid = threadIdx.x;
  const int mb = blockIdx.x & 63, hq = blockIdx.x >> 6;
  const int m = mb * 256 + tid;
  float acc[NG];
#pragma unroll
  for (int g = 0; g < NG; ++g) acc[g] = 0.f;
  const int h0 = hq * 64;
  for (int hh = 0; hh < 64; ++hh) {
    const int h = h0 + hh;
    float w = W2b[(size_t)h * MBC + m];
    const float* gr = Gbt + h * NG;
#pragma unroll
    for (int g = 0; g < NG; ++g) acc[g] += gr[g] * w;
  }
#pragma unroll
  for (int g = 0; g < NG; ++g)
    Pb[(size_t)(hq * NG + g) * MBC + m] = acc[g];
}
__global__ void k_mb2(const float* __restrict__ Pb, float* __restrict__ MBf) {
  const size_t i4 = ((size_t)blockIdx.x * 256 + threadIdx.x) * 4;
  const size_t Q = (size_t)NG * MBC;
  float4v s = *(const float4v*)(Pb + i4);
  s += *(const float4v*)(Pb + Q + i4);
  s += *(const float4v*)(Pb + 2 * Q + i4);
  s += *(const float4v*)(Pb + 3 * Q + i4);
  *(float4v*)(MBf + i4) = s;
}
__launch_bounds__(256)
__global__ void k_mbS(const float* __restrict__ W2b, const float* __restrict__ Gbt,
                      float* __restrict__ MBf) {
  const int tid = threadIdx.x;
  const int m = blockIdx.x * 256 + tid;
  float acc[NG];
#pragma unroll
  for (int g = 0; g < NG; ++g) acc[g] = 0.f;
  for (int h = 0; h < NH; ++h) {
    float w = W2b[(size_t)h * MBC + m];
    const float* gr = Gbt + h * NG;
#pragma unroll
    for (int g = 0; g < NG; ++g) acc[g] += gr[g] * w;
  }
#pragma unroll
  for (int g = 0; g < NG; ++g) MBf[(size_t)g * MBC + m] = acc[g];
}

// x0 -> packed hi|lo state
__global__ void k_x0(const float* __restrict__ x0, unsigned* __restrict__ Xst) {
  int idx = blockIdx.x * 256 + threadIdx.x;
  float x = x0[idx];
  unsigned short hs, ls;
  split_hl(x, hs, ls);
  Xst[idx] = (unsigned)hs | ((unsigned)ls << 16);
}

// ---------------- fused pipeline kernel (1024 thr) ----------------
// blocks [0, nroll): rollout chains (16 waves; thread = (i = tid>>2, jq = tid&3)).
//   COALESCED j-slice: thread covers j in {jq*8 + q*32 + e} so 4 consecutive
//   lanes read 64B contiguous (16 tx/wave-load instead of 64).
// blocks [nroll, nroll+160): pre role — wave-uniform scalar L loads (no LDS).
__launch_bounds__(1024)
__global__ void k_pr(const unsigned short* Arh, const unsigned char* Arl,
                     const unsigned short* Brh, const unsigned char* Brl,
                     unsigned short* Awh, unsigned char* Awl,
                     unsigned short* Bwh, unsigned char* Bwl,
                     const float* __restrict__ Lf,
                     const float* __restrict__ MGf, const float* __restrict__ MBf,
                     const float* __restrict__ b2a, const float* __restrict__ V,
                     const unsigned short* __restrict__ uhg,
                     const unsigned short* __restrict__ ulg,
                     unsigned* __restrict__ Xst, float* __restrict__ out,
                     int nroll, int t0r, int tnr, int t0p, int tnp) {
  __shared__ __align__(16) unsigned short xb[1024];   // roll x (hi/lo, dbuf)
  const int tid = threadIdx.x;
  const int bid = blockIdx.x;

  if (bid < nroll) {
    // ===== rollout role =====
    __builtin_amdgcn_s_setprio(1);
    const int b = bid;
    const int i = tid >> 2, jq = tid & 3;
    if (tid < 256) {
      unsigned pxx = Xst[b * 256 + tid];
      xb[tid] = (unsigned short)(pxx & 0xffffu);
      xb[512 + tid] = (unsigned short)(pxx >> 16);
    }
    __syncthreads();
    int cur = 0;
    for (int tt = 0; tt < tnr; ++tt) {
      const int t = t0r + tt;
      const int r = tt * NB + b;
      const size_t roA = (size_t)r * MA + (size_t)i * NS;     // elem base of row i
      const size_t roB = (size_t)r * MBC + (size_t)i * NA;
      const size_t rou = ((size_t)t * NB + b) * NA;
      const float vstep = V[((size_t)t * NB + b) * NS + i];
      // B/u: 2 chunks of 8 elems at jq*8 + qb*32 (coalesced)
      uint4v bh[2], uh[2], ul[2];
      uint2v bl2[2];
#pragma unroll
      for (int qb = 0; qb < 2; ++qb) {
        const int jo = jq * 8 + qb * 32;
        bh[qb]  = *(const uint4v*)(Brh + roB + jo);
        bl2[qb] = *(const uint2v*)(Brl + roB + jo);
        uh[qb]  = *(const uint4v*)(uhg + rou + jo);
        ul[qb]  = *(const uint4v*)(ulg + rou + jo);
      }
      const unsigned short* xhp = xb + cur * 256;
      const unsigned short* xlp = xb + 512 + cur * 256;
      float s1 = 0.f, s2 = 0.f;
#pragma unroll
      for (int q = 0; q < 8; ++q) {
        const int jo = jq * 8 + q * 32;
        uint4v a4 = *(const uint4v*)(Arh + roA + jo);
        uint2v l2 = *(const uint2v*)(Arl + roA + jo);   // 8 e5m2 bytes
        uint4v xh4 = *(const uint4v*)(xhp + jo);
        uint4v xl4 = *(const uint4v*)(xlp + jo);
#pragma unroll
        for (int p = 0; p < 4; ++p) {
          s1 = fdot2f(as_h2(a4[p]), as_h2(xh4[p]), s1);
          s2 = fdot2f(as_h2(a4[p]), as_h2(xl4[p]), s2);
        }
        h2 p01, p23;
        dec4(l2[0], p01, p23);
        s2 = fdot2f(p01, as_h2(xh4[0]), s2);
        s2 = fdot2f(p23, as_h2(xh4[1]), s2);
        dec4(l2[1], p01, p23);
        s2 = fdot2f(p01, as_h2(xh4[2]), s2);
        s2 = fdot2f(p23, as_h2(xh4[3]), s2);
      }
      // B·u (16 cols per thread, 2 chunks)
#pragma unroll
      for (int qb = 0; qb < 2; ++qb) {
#pragma unroll
        for (int p = 0; p < 4; ++p) {
          s1 = fdot2f(as_h2(bh[qb][p]), as_h2(uh[qb][p]), s1);
          s2 = fdot2f(as_h2(bh[qb][p]), as_h2(ul[qb][p]), s2);
        }
        h2 p01, p23;
        dec4(bl2[qb][0], p01, p23);
        s2 = fdot2f(p01, as_h2(uh[qb][0]), s2);
        s2 = fdot2f(p23, as_h2(uh[qb][1]), s2);
        dec4(bl2[qb][1], p01, p23);
        s2 = fdot2f(p01, as_h2(uh[qb][2]), s2);
        s2 = fdot2f(p23, as_h2(uh[qb][3]), s2);
      }
      float d = s1 + s2 * LO_INV;
      d += __shfl_xor(d, 1);
      d += __shfl_xor(d, 2);
      if (jq == 0) {
        float xn = d + vstep;
        out[((size_t)b * NT + t) * NS + i] = xn;
        unsigned short hs, ls;
        split_hl(xn, hs, ls);
        xb[(cur ^ 1) * 256 + i] = hs;
        xb[512 + (cur ^ 1) * 256 + i] = ls;
      }
      __syncthreads();
      cur ^= 1;
    }
    if (tid < 256) {
      unsigned pxx = (unsigned)xb[cur * 256 + tid] |
                     ((unsigned)xb[512 + cur * 256 + tid] << 16);
      Xst[b * 256 + tid] = pxx;
    }
    __builtin_amdgcn_s_setprio(0);
  } else {
    // ===== pre role: f32 VALU materialization of A and B (next chunk) =====
    // L rows are wave-uniform -> scalar (s_load) path; no LDS, no barriers.
    const int pb = bid - nroll;          // 0..159
    const int cu = pb >> 1, hf = pb & 1;
    const int R = tnp * NB;              // chunk rows
    const int per = (R + 1) >> 1;
    const int r0 = hf * per;
    const int r1 = (r0 + per < R) ? (r0 + per) : R;
    const bool isA = (cu < 64);
    const int m = isA ? (cu * 1024 + tid) : ((cu - 64) * 1024 + tid);
    const int MC = isA ? MA : MBC;
    const float* __restrict__ MF = isA ? MGf : MBf;
    unsigned short* Wh = isA ? Awh : Bwh;
    unsigned char* Wl = isA ? Awl : Bwl;
    float4v mg4[NG / 4];
#pragma unroll
    for (int g4 = 0; g4 < NG / 4; ++g4)
#pragma unroll
      for (int k = 0; k < 4; ++k)
        mg4[g4][k] = MF[(size_t)(g4 * 4 + k) * MC + m];
    const float b2v = isA ? b2a[m] : 0.f;
#pragma unroll 2
    for (int r = r0; r < r1; ++r) {
      const float* __restrict__ Lr = Lf + ((size_t)(t0p * NB) + r) * NG;
      float4v a4 = {0.f, 0.f, 0.f, 0.f};
#pragma unroll
      for (int g4 = 0; g4 < NG / 4; ++g4) {
        float4v L4 = *(const float4v*)(Lr + g4 * 4);
        a4 += L4 * mg4[g4];
      }
      float v = (a4[0] + a4[1]) + (a4[2] + a4[3]) + b2v;
      unsigned short hs, ls;
      split_hl(v, hs, ls);
      const size_t gb = (size_t)r * MC + m;
      Wh[gb] = hs;
      Wl[gb] = lo_e5m2(ls);
    }
  }
}

// ---------------- launch ----------------

static inline int imin(int a, int b) { return a < b ? a : b; }

extern "C" void kernel_launch(void* const* d_in, const int* in_sizes, int n_in,
                              void* d_out, int out_size, void* d_ws, size_t ws_size,
                              hipStream_t stream) {
  const float* x0  = (const float*)d_in[0];
  const float* ctx = (const float*)d_in[1];
  const float* usin = (const float*)d_in[2];
  const float* W1a = (const float*)d_in[3];
  const float* b1a = (const float*)d_in[4];
  const float* W2a = (const float*)d_in[5];
  const float* b2a = (const float*)d_in[6];
  const float* W1b = (const float*)d_in[7];
  const float* b1b = (const float*)d_in[8];
  const float* W2b = (const float*)d_in[9];
  const float* b2b = (const float*)d_in[10];
  float* out = (float*)d_out;

  const size_t perTAh = (size_t)NB * MA * 2;         //  8,388,608 per t
  const size_t perTAl = (size_t)NB * MA;             //  4,194,304 per t
  const size_t perTBh = (size_t)NB * MBC * 2;        //  2,097,152 per t
  const size_t perTBl = (size_t)NB * MBC;            //  1,048,576 per t
  const size_t perTall = perTAh + perTAl + perTBh + perTBl;  // 15,728,640
  const size_t szMGf = (size_t)NG * MA * 4;          //  8,388,608
  const size_t szMBf = (size_t)NG * MBC * 4;         //  2,097,152
  const size_t szLf  = (size_t)NT * NB * NG * 4;     //    409,600
  const size_t szGt  = (size_t)NH * NG * 4;          //     32,768 each
  const size_t szU   = (size_t)NT * NB * NA * 2;     //    409,600 each
  const size_t szV   = (size_t)NT * NB * NS * 4;     //  3,276,800
  const size_t szXst = (size_t)NB * NS * 4;          //     65,536
  const size_t szPp  = (size_t)4 * NG * MA * 4;      // 33,554,432 (aliases A-bufs)
  const size_t szPb  = (size_t)4 * NG * MBC * 4;     //  8,388,608

  const size_t fixed = szMGf + szMBf + szLf + 2 * szGt + 2 * szU + szV + szXst;

  size_t avail = (ws_size > fixed) ? (ws_size - fixed) : 0;
  bool dbuf = true;
  int Tc = (int)(avail / (2 * perTall));
  if (Tc > 5) Tc = 5;   // 2 x 78.6 MB live A/B set — comfortably L3-resident
  if (Tc < 1) {
    dbuf = false;
    Tc = (int)(avail / perTall);
    if (Tc > 5) Tc = 5;
    if (Tc < 1) Tc = 1;
  }

  char* p = (char*)d_ws;
  unsigned short* A0h = (unsigned short*)p; p += (size_t)Tc * perTAh;
  unsigned char*  A0l = (unsigned char*)p;  p += (size_t)Tc * perTAl;
  unsigned short* B0h = (unsigned short*)p; p += (size_t)Tc * perTBh;
  unsigned char*  B0l = (unsigned char*)p;  p += (size_t)Tc * perTBl;
  unsigned short *A1h = A0h, *B1h = B0h;
  unsigned char  *A1l = A0l, *B1l = B0l;
  if (dbuf) {
    A1h = (unsigned short*)p; p += (size_t)Tc * perTAh;
    A1l = (unsigned char*)p;  p += (size_t)Tc * perTAl;
    B1h = (unsigned short*)p; p += (size_t)Tc * perTBh;
    B1l = (unsigned char*)p;  p += (size_t)Tc * perTBl;
  }
  float* MGf = (float*)p; p += szMGf;
  float* MBf = (float*)p; p += szMBf;
  float* Lf  = (float*)p; p += szLf;
  float* Gt  = (float*)p; p += szGt;
  float* Gbt = (float*)p; p += szGt;
  unsigned short* uhg = (unsigned short*)p; p += szU;
  unsigned short* ulg = (unsigned short*)p; p += szU;
  float* Vg  = (float*)p; p += szV;
  unsigned* Xst = (unsigned*)p;

  // partial-sum scratch aliases the A/B buffers (used strictly before first k_pr)
  const size_t abbytes = (dbuf ? 2 : 1) * (size_t)Tc * perTall;
  const bool fast_red = abbytes >= (szPp + szPb);
  float* Pp = (float*)A0h;
  float* Pb = Pp + szPp / 4;

  k_g<<<NG, NH, 0, stream>>>(W1a, b1a, W1b, b1b, Gt, Gbt);
  k_lag<<<(NT * NB + 255) / 256, 256, 0, stream>>>(ctx, Lf);
  k_v<<<NT * NB, NS, 0, stream>>>(b2b, usin, Vg);
  k_u2<<<(NT * NB * NA) / 256, 256, 0, stream>>>(usin, uhg, ulg);
  k_x0<<<NB, 256, 0, stream>>>(x0, Xst);
  if (fast_red) {
    k_mg1<<<1024, 256, 0, stream>>>(W2a, Gt, Pp);
    k_mg2<<<(int)((size_t)NG * MA / 1024), 256, 0, stream>>>(Pp, MGf);
    k_mb1<<<256, 256, 0, stream>>>(W2b, Gbt, Pb);
    k_mb2<<<(int)((size_t)NG * MBC / 1024), 256, 0, stream>>>(Pb, MBf);
  } else {
    k_mgS<<<MA / 256, 256, 0, stream>>>(W2a, Gt, MGf);
    k_mbS<<<MBC / 256, 256, 0, stream>>>(W2b, Gbt, MBf);
  }

  (void)in_sizes; (void)n_in; (void)out_size;

  const int nc = (NT + Tc - 1) / Tc;
  if (dbuf) {
    // pipelined: launch L runs roll(chunk L-1) || pre(chunk L); 64+160 blocks
    for (int L = 0; L <= nc; ++L) {
      const int rc = L - 1, pc = L;
      const int nroll = (rc >= 0) ? NB : 0;
      const int t0r = (rc >= 0) ? rc * Tc : 0;
      const int tnr = (rc >= 0) ? imin(Tc, NT - t0r) : 0;
      const int t0p = (pc < nc) ? pc * Tc : 0;
      const int tnp = (pc < nc) ? imin(Tc, NT - t0p) : 0;
      const int grid = nroll + (tnp > 0 ? 160 : 0);
      const unsigned short* Arh = ((rc & 1) ? A1h : A0h);
      const unsigned char*  Arl = ((rc & 1) ? A1l : A0l);
      const unsigned short* Brh = ((rc & 1) ? B1h : B0h);
      const unsigned char*  Brl = ((rc & 1) ? B1l : B0l);
      unsigned short* Awh = ((pc & 1) ? A1h : A0h);
      unsigned char*  Awl = ((pc & 1) ? A1l : A0l);
      unsigned short* Bwh = ((pc & 1) ? B1h : B0h);
      unsigned char*  Bwl = ((pc & 1) ? B1l : B0l);
      k_pr<<<grid, 1024, 0, stream>>>(Arh, Arl, Brh, Brl, Awh, Awl, Bwh, Bwl,
                                      Lf, MGf, MBf, b2a, Vg, uhg, ulg, Xst, out,
                                      nroll, t0r, tnr, t0p, tnp);
    }
  } else {
    for (int c = 0; c < nc; ++c) {
      const int t0 = c * Tc, tn = imin(Tc, NT - t0);
      k_pr<<<160, 1024, 0, stream>>>(A0h, A0l, B0h, B0l, A0h, A0l, B0h, B0l,
                                     Lf, MGf, MBf, b2a, Vg, uhg, ulg, Xst, out,
                                     0, 0, 0, t0, tn);
      k_pr<<<NB, 1024, 0, stream>>>(A0h, A0l, B0h, B0l, A0h, A0l, B0h, B0l,
                                    Lf, MGf, MBf, b2a, Vg, uhg, ulg, Xst, out,
                                    NB, t0, tn, 0, 0);
    }
  }
}